// Round 1
// baseline (1330.702 us; speedup 1.0000x reference)
//
#include <hip/hip_runtime.h>
#include <math.h>

#define U 128
#define GAMMA 28
#define TB 16        // batch elements per block
#define HB 8         // batch elements per half (TB/2)
#define NT 256
#define NSTEPS 75    // 48 encoder + 27 feedback

__device__ __forceinline__ float sigmoid_f(float x) { return 1.0f / (1.0f + __expf(-x)); }
__device__ __forceinline__ float tanh_f(float x)    { return 1.0f - 2.0f / (1.0f + __expf(2.0f * x)); }
__device__ __forceinline__ float softplus_f(float x) {
    // stable: max(x,0) + log1p(exp(-|x|))
    return fmaxf(x, 0.0f) + log1pf(__expf(-fabsf(x)));
}

__global__ __launch_bounds__(NT, 2) void fib_rnn_kernel(
    const float* __restrict__ inp,      // (B,49,1)
    const float* __restrict__ Kw,       // (1,384)
    const float* __restrict__ Rw,       // (128,384)
    const float* __restrict__ bias,     // (2,384)
    const float* __restrict__ dv_loc,   // (258)
    const float* __restrict__ dv_rho,   // (258)
    const float* __restrict__ dv_eps,   // (28,258)
    const float* __restrict__ samp,     // (27,B,1)
    float* __restrict__ out,            // (B,28,2)
    int B)
{
    __shared__ __align__(16) float h_lds[TB][U];
    __shared__ float in_lds[TB][48];
    __shared__ float y_lds[TB];
    __shared__ float wsum[4][2 * HB];

    const int tid  = threadIdx.x;
    const int j    = tid & (U - 1);     // gate column 0..127
    const int half = tid >> 7;          // 0 or 1
    const int bb   = half * HB;         // local batch base
    const int wave = tid >> 6;          // 0..3
    const int lane = tid & 63;
    const int b0   = blockIdx.x * TB;   // global batch base

    // stage encoder inputs (first 48 of 49 timesteps)
    for (int i = tid; i < TB * 48; i += NT) {
        int bl = i / 48, tt = i - bl * 48;
        in_lds[bl][tt] = inp[(size_t)(b0 + bl) * 49 + tt];
    }
    // h0 = 0
    for (int i = tid; i < TB * U; i += NT)
        (&h_lds[0][0])[i] = 0.0f;

    // per-thread stationary GRU params
    const float Kz = Kw[j], Kr = Kw[j + U], Kh = Kw[j + 2 * U];
    const float bz  = bias[j]         + bias[384 + j];          // b0z+b1z (foldable)
    const float br  = bias[j + U]     + bias[384 + j + U];      // b0r+b1r
    const float bhx = bias[j + 2 * U];                          // b0h (outside r*)
    const float bhh = bias[384 + j + 2 * U];                    // b1h (inside r*)

    const float Cc = 0.5413248546f;   // log(expm1(1))
    // dense_var rows 2j, 2j+1: w = loc + (1e-5 + 0.02*softplus(C+rho))*eps
    const float wl0 = dv_loc[2 * j], wl1 = dv_loc[2 * j + 1];
    const float ws0 = 1e-5f + 0.02f * softplus_f(Cc + dv_rho[2 * j]);
    const float ws1 = 1e-5f + 0.02f * softplus_f(Cc + dv_rho[2 * j + 1]);

    float wbl0 = 0.f, wbl1 = 0.f, wbs0 = 0.f, wbs1 = 0.f;
    if (tid < TB) {  // bias rows 256,257 for the x2 finishers
        wbl0 = dv_loc[256]; wbs0 = 1e-5f + 0.02f * softplus_f(Cc + dv_rho[256]);
        wbl1 = dv_loc[257]; wbs1 = 1e-5f + 0.02f * softplus_f(Cc + dv_rho[257]);
    }
    __syncthreads();

    float hnew[HB];

    for (int step = 0; step < NSTEPS; ++step) {
        // ---- recurrent matmul: acc[c] = sum_k h[b][k] * R[k][c], c in {j, j+128, j+256}
        float accz[HB], accr[HB], acch[HB];
        #pragma unroll
        for (int b = 0; b < HB; ++b) { accz[b] = 0.f; accr[b] = 0.f; acch[b] = 0.f; }

        #pragma unroll 4
        for (int k4 = 0; k4 < U / 4; ++k4) {
            float4 hv[HB];
            #pragma unroll
            for (int b = 0; b < HB; ++b)
                hv[b] = *reinterpret_cast<const float4*>(&h_lds[bb + b][k4 * 4]);  // broadcast
            #pragma unroll
            for (int kk = 0; kk < 4; ++kk) {
                const float* rrow = Rw + (size_t)(k4 * 4 + kk) * 384;
                const float rz = rrow[j];            // coalesced 256B/wave
                const float rr = rrow[j + U];
                const float rh = rrow[j + 2 * U];
                #pragma unroll
                for (int b = 0; b < HB; ++b) {
                    const float hb = reinterpret_cast<const float*>(&hv[b])[kk];
                    accz[b] = fmaf(hb, rz, accz[b]);
                    accr[b] = fmaf(hb, rr, accr[b]);
                    acch[b] = fmaf(hb, rh, acch[b]);
                }
            }
        }

        // ---- gates (reads h_lds old values; no writes yet)
        #pragma unroll
        for (int b = 0; b < HB; ++b) {
            const float x    = (step < 48) ? in_lds[bb + b][step] : y_lds[bb + b];
            const float hold = h_lds[bb + b][j];
            const float z  = sigmoid_f(fmaf(x, Kz, bz) + accz[b]);
            const float r  = sigmoid_f(fmaf(x, Kr, br) + accr[b]);
            const float hh = tanh_f(fmaf(x, Kh, bhx) + r * (acch[b] + bhh));
            hnew[b] = z * hold + (1.f - z) * hh;
        }
        __syncthreads();   // all reads of old h complete
        #pragma unroll
        for (int b = 0; b < HB; ++b)
            h_lds[bb + b][j] = hnew[b];

        const int s = step - 47;   // dense_var eps index: step47->0, 48..74 -> 1..27
        if (s >= 0) {
            // per-thread dense_var weights for this step
            const float2 e = *reinterpret_cast<const float2*>(&dv_eps[s * 258 + 2 * j]);
            const float w0 = fmaf(ws0, e.x, wl0);
            const float w1 = fmaf(ws1, e.y, wl1);
            float pv[2 * HB];
            #pragma unroll
            for (int b = 0; b < HB; ++b) {
                pv[2 * b]     = hnew[b] * w0;
                pv[2 * b + 1] = hnew[b] * w1;
            }
            // butterfly reduce over the wave's 64 j-lanes
            #pragma unroll
            for (int off = 32; off >= 1; off >>= 1) {
                #pragma unroll
                for (int i = 0; i < 2 * HB; ++i)
                    pv[i] += __shfl_xor(pv[i], off, 64);
            }
            if (lane == 0) {
                #pragma unroll
                for (int i = 0; i < 2 * HB; ++i)
                    wsum[wave][i] = pv[i];
            }
            __syncthreads();   // h writes + wsum visible
            if (tid < TB) {
                const int bl  = tid;
                const int w0i = (bl >= HB) ? 2 : 0;          // wave pair for this half
                const int ii  = (bl & (HB - 1)) * 2;
                const float eb0 = dv_eps[s * 258 + 256];
                const float eb1 = dv_eps[s * 258 + 257];
                const float x20 = wsum[w0i][ii]     + wsum[w0i + 1][ii]     + fmaf(wbs0, eb0, wbl0);
                const float x21 = wsum[w0i][ii + 1] + wsum[w0i + 1][ii + 1] + fmaf(wbs1, eb1, wbl1);
                const float scale = 1e-5f + 0.05f * softplus_f(Cc + x21);
                const size_t ob = ((size_t)(b0 + bl) * GAMMA + s) * 2;
                out[ob]     = x20;     // loc
                out[ob + 1] = scale;   // transformed scale
                if (s < GAMMA - 1)     // feedback input for next GRU step
                    y_lds[bl] = fmaf(scale, samp[(size_t)s * B + b0 + bl], x20);
            }
            __syncthreads();   // y_lds visible for next step's gate phase
        } else {
            __syncthreads();   // h writes visible for next matmul
        }
    }
}

extern "C" void kernel_launch(void* const* d_in, const int* in_sizes, int n_in,
                              void* d_out, int out_size, void* d_ws, size_t ws_size,
                              hipStream_t stream) {
    const float* inp    = (const float*)d_in[0];
    const float* Kw     = (const float*)d_in[1];
    const float* Rw     = (const float*)d_in[2];
    const float* bias   = (const float*)d_in[3];
    const float* dv_loc = (const float*)d_in[4];
    const float* dv_rho = (const float*)d_in[5];
    const float* dv_eps = (const float*)d_in[6];
    const float* samp   = (const float*)d_in[7];
    float* out = (float*)d_out;
    const int B = in_sizes[0] / 49;   // 8192
    dim3 grid(B / TB), block(NT);
    hipLaunchKernelGGL(fib_rnn_kernel, grid, block, 0, stream,
                       inp, Kw, Rw, bias, dv_loc, dv_rho, dv_eps, samp, out, B);
}

// Round 3
// 345.733 us; speedup vs baseline: 3.8489x; 3.8489x over previous
//
#include <hip/hip_runtime.h>
#include <math.h>

#define U 128
#define GAMMA 28
#define TB 32        // batch rows per block (2 MFMA row-groups of 16)
#define NT 512       // 8 waves
#define NSTEPS 75    // 48 encoder + 27 feedback

typedef short short8 __attribute__((ext_vector_type(8)));
typedef float floatx4 __attribute__((ext_vector_type(4)));

__device__ __forceinline__ float sigmoid_f(float x) { return 1.0f / (1.0f + __expf(-x)); }
__device__ __forceinline__ float tanh_f(float x)    { return 1.0f - 2.0f / (1.0f + __expf(2.0f * x)); }
__device__ __forceinline__ float softplus_f(float x) {
    return fmaxf(x, 0.0f) + log1pf(__expf(-fabsf(x)));
}
__device__ __forceinline__ unsigned short f2bf(float f) {   // RNE float->bf16
    unsigned int u = __float_as_uint(f);
    u += 0x7fffu + ((u >> 16) & 1u);
    return (unsigned short)(u >> 16);
}
__device__ __forceinline__ float bf2f(unsigned short s) {
    return __uint_as_float(((unsigned int)s) << 16);
}

__global__ __launch_bounds__(NT, 2) void fib_rnn_kernel(
    const float* __restrict__ inp,      // (B,49,1)
    const float* __restrict__ Kw,       // (1,384)
    const float* __restrict__ Rw,       // (128,384)
    const float* __restrict__ bias,     // (2,384)
    const float* __restrict__ dv_loc,   // (258)
    const float* __restrict__ dv_rho,   // (258)
    const float* __restrict__ dv_eps,   // (28,258)
    const float* __restrict__ samp,     // (27,B,1)
    float* __restrict__ out,            // (B,28,2)
    int B)
{
    // h (bf16 hi/lo) in MFMA A-fragment order per 16-row group:
    // element (b16, j) at short-index ((j>>3)*16 + b16)*8 + (j&7)
    __shared__ __align__(16) unsigned short hA_hi[2][2048];
    __shared__ __align__(16) unsigned short hA_lo[2][2048];
    __shared__ float in_lds[TB][48];
    __shared__ float y_lds[TB];
    __shared__ float wsum[8][TB][2];

    const int tid  = threadIdx.x;
    const int wv   = tid >> 6;          // wave 0..7
    const int lane = tid & 63;
    const int q    = lane >> 4;         // quad 0..3
    const int m16  = lane & 15;
    const int r0   = q * 4;             // first row (within 16-group) of C regs
    const int b0   = blockIdx.x * TB;
    const int j    = wv * 16 + m16;     // this lane's gate column (0..127)

    // stage encoder inputs
    for (int i = tid; i < TB * 48; i += NT) {
        int bl = i / 48, tt = i - bl * 48;
        in_lds[bl][tt] = inp[(size_t)(b0 + bl) * 49 + tt];
    }
    for (int i = tid; i < 2 * 2048; i += NT) {
        (&hA_hi[0][0])[i] = 0; (&hA_lo[0][0])[i] = 0;
    }

    // ---- stationary R fragments, hi+lo bf16. Wave wv owns n-tiles {wv, wv+8, wv+16}
    // (z, r, h gate columns j = wv*16+m16 all land in the same lane/reg slot)
    short8 Rhi[3][4], Rlo[3][4];
    {
        const int tiles[3] = {wv, wv + 8, wv + 16};
        #pragma unroll
        for (int t = 0; t < 3; ++t) {
            const int c = tiles[t] * 16 + m16;
            #pragma unroll
            for (int kt = 0; kt < 4; ++kt) {
                #pragma unroll
                for (int e = 0; e < 8; ++e) {
                    const float v = Rw[(size_t)(kt * 32 + q * 8 + e) * 384 + c];
                    const unsigned short h = f2bf(v);
                    Rhi[t][kt][e] = (short)h;
                    Rlo[t][kt][e] = (short)f2bf(v - bf2f(h));
                }
            }
        }
    }

    // per-lane gate constants for column j
    const float Cc = 0.5413248546f;   // log(expm1(1))
    const float Kz  = Kw[j], Kr = Kw[j + U], Kh = Kw[j + 2 * U];
    const float bz  = bias[j]         + bias[384 + j];
    const float br  = bias[j + U]     + bias[384 + j + U];
    const float bhx = bias[j + 2 * U];
    const float bhh = bias[384 + j + 2 * U];
    const float wl0 = dv_loc[2 * j],  wl1 = dv_loc[2 * j + 1];
    const float ws0 = 1e-5f + 0.02f * softplus_f(Cc + dv_rho[2 * j]);
    const float ws1 = 1e-5f + 0.02f * softplus_f(Cc + dv_rho[2 * j + 1]);

    float wbl0 = 0.f, wbl1 = 0.f, wbs0 = 0.f, wbs1 = 0.f;
    if (tid < TB) {
        wbl0 = dv_loc[256]; wbs0 = 1e-5f + 0.02f * softplus_f(Cc + dv_rho[256]);
        wbl1 = dv_loc[257]; wbs1 = 1e-5f + 0.02f * softplus_f(Cc + dv_rho[257]);
    }

    // fp32 h state lives in registers: lane owns rows {g*16+r0+i}, col j
    float hprev[2][4];
    #pragma unroll
    for (int g = 0; g < 2; ++g)
        #pragma unroll
        for (int i = 0; i < 4; ++i) hprev[g][i] = 0.f;

    __syncthreads();

    for (int step = 0; step < NSTEPS; ++step) {
        // ---- recurrent matmul: preact[32][384] = h[32][128] @ R  (3-term bf16 split)
        floatx4 acc[2][3];
        #pragma unroll
        for (int g = 0; g < 2; ++g)
            #pragma unroll
            for (int t = 0; t < 3; ++t) acc[g][t] = (floatx4){0.f, 0.f, 0.f, 0.f};

        #pragma unroll
        for (int kt = 0; kt < 4; ++kt) {
            short8 Ah[2], Al[2];
            #pragma unroll
            for (int g = 0; g < 2; ++g) {
                Ah[g] = *reinterpret_cast<const short8*>(&hA_hi[g][kt * 512 + lane * 8]);
                Al[g] = *reinterpret_cast<const short8*>(&hA_lo[g][kt * 512 + lane * 8]);
            }
            #pragma unroll
            for (int g = 0; g < 2; ++g) {
                #pragma unroll
                for (int t = 0; t < 3; ++t) {
                    acc[g][t] = __builtin_amdgcn_mfma_f32_16x16x32_bf16(Ah[g], Rhi[t][kt], acc[g][t], 0, 0, 0);
                    acc[g][t] = __builtin_amdgcn_mfma_f32_16x16x32_bf16(Al[g], Rhi[t][kt], acc[g][t], 0, 0, 0);
                    acc[g][t] = __builtin_amdgcn_mfma_f32_16x16x32_bf16(Ah[g], Rlo[t][kt], acc[g][t], 0, 0, 0);
                }
            }
        }

        // ---- gates (lane owns rows g*16+r0..+3, col j); h state stays fp32 in regs
        float hn[2][4];
        #pragma unroll
        for (int g = 0; g < 2; ++g) {
            #pragma unroll
            for (int i = 0; i < 4; ++i) {
                const int b = g * 16 + r0 + i;
                const float x = (step < 48) ? in_lds[b][step] : y_lds[b];
                const float z  = sigmoid_f(acc[g][0][i] + fmaf(x, Kz, bz));
                const float r  = sigmoid_f(acc[g][1][i] + fmaf(x, Kr, br));
                const float hh = tanh_f(fmaf(x, Kh, bhx) + r * (acc[g][2][i] + bhh));
                hn[g][i] = z * hprev[g][i] + (1.f - z) * hh;
                hprev[g][i] = hn[g][i];
            }
        }
        __syncthreads();   // all A-fragment reads of old h complete

        #pragma unroll
        for (int g = 0; g < 2; ++g) {
            #pragma unroll
            for (int i = 0; i < 4; ++i) {
                const int idx = ((j >> 3) * 16 + (r0 + i)) * 8 + (j & 7);
                const unsigned short hi = f2bf(hn[g][i]);
                hA_hi[g][idx] = hi;
                hA_lo[g][idx] = f2bf(hn[g][i] - bf2f(hi));
            }
        }

        const int s = step - 47;
        if (s >= 0) {
            // dense_var: x2[b][o] = sum_j h[b][j] * w_o(j) + bias_o
            const float2 e = *reinterpret_cast<const float2*>(&dv_eps[s * 258 + 2 * j]);
            const float w0 = fmaf(ws0, e.x, wl0);
            const float w1 = fmaf(ws1, e.y, wl1);
            float pv[16];
            #pragma unroll
            for (int g = 0; g < 2; ++g)
                #pragma unroll
                for (int i = 0; i < 4; ++i) {
                    pv[(g * 4 + i) * 2]     = hn[g][i] * w0;
                    pv[(g * 4 + i) * 2 + 1] = hn[g][i] * w1;
                }
            #pragma unroll
            for (int off = 8; off >= 1; off >>= 1) {
                #pragma unroll
                for (int k = 0; k < 16; ++k)
                    pv[k] += __shfl_xor(pv[k], off, 64);
            }
            if (m16 == 0) {
                #pragma unroll
                for (int g = 0; g < 2; ++g)
                    #pragma unroll
                    for (int i = 0; i < 4; ++i)
                        *reinterpret_cast<float2*>(&wsum[wv][g * 16 + r0 + i][0]) =
                            make_float2(pv[(g * 4 + i) * 2], pv[(g * 4 + i) * 2 + 1]);
            }
            __syncthreads();   // h writes + wsum visible
            if (tid < TB) {
                const int bl = tid;
                const float eb0 = dv_eps[s * 258 + 256];
                const float eb1 = dv_eps[s * 258 + 257];
                float x20 = fmaf(wbs0, eb0, wbl0);
                float x21 = fmaf(wbs1, eb1, wbl1);
                #pragma unroll
                for (int w = 0; w < 8; ++w) {
                    x20 += wsum[w][bl][0];
                    x21 += wsum[w][bl][1];
                }
                const float scale = 1e-5f + 0.05f * softplus_f(Cc + x21);
                const size_t ob = ((size_t)(b0 + bl) * GAMMA + s) * 2;
                out[ob]     = x20;
                out[ob + 1] = scale;
                if (s < GAMMA - 1)
                    y_lds[bl] = fmaf(scale, samp[(size_t)s * B + b0 + bl], x20);
            }
            __syncthreads();   // y_lds visible for next step
        } else {
            __syncthreads();   // h writes visible for next matmul
        }
    }
}

extern "C" void kernel_launch(void* const* d_in, const int* in_sizes, int n_in,
                              void* d_out, int out_size, void* d_ws, size_t ws_size,
                              hipStream_t stream) {
    const float* inp    = (const float*)d_in[0];
    const float* Kw     = (const float*)d_in[1];
    const float* Rw     = (const float*)d_in[2];
    const float* bias   = (const float*)d_in[3];
    const float* dv_loc = (const float*)d_in[4];
    const float* dv_rho = (const float*)d_in[5];
    const float* dv_eps = (const float*)d_in[6];
    const float* samp   = (const float*)d_in[7];
    float* out = (float*)d_out;
    const int B = in_sizes[0] / 49;   // 8192
    dim3 grid(B / TB), block(NT);
    hipLaunchKernelGGL(fib_rnn_kernel, grid, block, 0, stream,
                       inp, Kw, Rw, bias, dv_loc, dv_rho, dv_eps, samp, out, B);
}

// Round 5
// 276.969 us; speedup vs baseline: 4.8045x; 1.2483x over previous
//
#include <hip/hip_runtime.h>
#include <math.h>

#define U 128
#define GAMMA 28
#define TB 16        // batch rows per block (one MFMA row-group)
#define NT 512       // 8 waves
#define NSTEPS 75    // 48 encoder + 27 feedback

typedef _Float16 half8 __attribute__((ext_vector_type(8)));
typedef float floatx4 __attribute__((ext_vector_type(4)));

__device__ __forceinline__ float sigmoid_f(float x) { return 1.0f / (1.0f + __expf(-x)); }
__device__ __forceinline__ float tanh_f(float x)    { return 1.0f - 2.0f / (1.0f + __expf(2.0f * x)); }
__device__ __forceinline__ float softplus_f(float x) {
    return fmaxf(x, 0.0f) + log1pf(__expf(-fabsf(x)));
}

__global__ __launch_bounds__(NT, 4) void fib_rnn_kernel(
    const float* __restrict__ inp,      // (B,49,1)
    const float* __restrict__ Kw,       // (1,384)
    const float* __restrict__ Rw,       // (128,384)
    const float* __restrict__ bias,     // (2,384)
    const float* __restrict__ dv_loc,   // (258)
    const float* __restrict__ dv_rho,   // (258)
    const float* __restrict__ dv_eps,   // (28,258)
    const float* __restrict__ samp,     // (27,B,1)
    float* __restrict__ out,            // (B,28,2)
    int B)
{
    // h (fp16) in MFMA A-fragment order:
    // element (b, j) at half-index ((j>>3)*16 + b)*8 + (j&7)
    __shared__ __align__(16) _Float16 hA[2048];
    __shared__ float in_lds[TB][48];
    __shared__ float y_lds[TB];
    __shared__ float wsum[8][TB][2];

    const int tid  = threadIdx.x;
    const int wv   = tid >> 6;          // wave 0..7
    const int lane = tid & 63;
    const int q    = lane >> 4;         // quad 0..3
    const int m16  = lane & 15;
    const int r0   = q * 4;             // first batch row of this lane's C regs
    const int b0   = blockIdx.x * TB;
    const int j    = wv * 16 + m16;     // this lane's gate column (0..127)

    // stage encoder inputs
    for (int i = tid; i < TB * 48; i += NT) {
        int bl = i / 48, tt = i - bl * 48;
        in_lds[bl][tt] = inp[(size_t)(b0 + bl) * 49 + tt];
    }
    for (int i = tid; i < 2048; i += NT) hA[i] = (_Float16)0.f;

    // ---- stationary R fragments (fp16). Wave wv owns n-tiles {wv, wv+8, wv+16}
    // (z, r, h gate columns j = wv*16+m16 all land in the same lane/reg slot)
    half8 Rb[3][4];
    {
        const int tiles[3] = {wv, wv + 8, wv + 16};
        #pragma unroll
        for (int t = 0; t < 3; ++t) {
            const int c = tiles[t] * 16 + m16;
            #pragma unroll
            for (int kt = 0; kt < 4; ++kt) {
                #pragma unroll
                for (int e = 0; e < 8; ++e)
                    Rb[t][kt][e] = (_Float16)Rw[(size_t)(kt * 32 + q * 8 + e) * 384 + c];
            }
        }
    }

    // per-lane gate constants for column j
    const float Cc = 0.5413248546f;   // log(expm1(1))
    const float Kz  = Kw[j], Kr = Kw[j + U], Kh = Kw[j + 2 * U];
    const float bz  = bias[j]         + bias[384 + j];
    const float br  = bias[j + U]     + bias[384 + j + U];
    const float bhx = bias[j + 2 * U];
    const float bhh = bias[384 + j + 2 * U];
    const float wl0 = dv_loc[2 * j],  wl1 = dv_loc[2 * j + 1];
    const float ws0 = 1e-5f + 0.02f * softplus_f(Cc + dv_rho[2 * j]);
    const float ws1 = 1e-5f + 0.02f * softplus_f(Cc + dv_rho[2 * j + 1]);

    float wbl0 = 0.f, wbl1 = 0.f, wbs0 = 0.f, wbs1 = 0.f;
    if (tid < TB) {
        wbl0 = dv_loc[256]; wbs0 = 1e-5f + 0.02f * softplus_f(Cc + dv_rho[256]);
        wbl1 = dv_loc[257]; wbs1 = 1e-5f + 0.02f * softplus_f(Cc + dv_rho[257]);
    }

    // fp32 h state in registers: lane owns rows r0..r0+3, col j
    float hprev[4] = {0.f, 0.f, 0.f, 0.f};

    __syncthreads();

    for (int step = 0; step < NSTEPS; ++step) {
        // ---- recurrent matmul: preact[16][384] = h[16][128] @ R  (fp16 MFMA)
        floatx4 acc[3];
        #pragma unroll
        for (int t = 0; t < 3; ++t) acc[t] = (floatx4){0.f, 0.f, 0.f, 0.f};

        #pragma unroll
        for (int kt = 0; kt < 4; ++kt) {
            const half8 Ah = *reinterpret_cast<const half8*>(&hA[kt * 512 + lane * 8]);
            #pragma unroll
            for (int t = 0; t < 3; ++t)
                acc[t] = __builtin_amdgcn_mfma_f32_16x16x32_f16(Ah, Rb[t][kt], acc[t], 0, 0, 0);
        }

        // ---- gates (lane owns rows r0..r0+3, col j); h state stays fp32 in regs
        float hn[4];
        #pragma unroll
        for (int i = 0; i < 4; ++i) {
            const int b = r0 + i;
            const float x = (step < 48) ? in_lds[b][step] : y_lds[b];
            const float z  = sigmoid_f(acc[0][i] + fmaf(x, Kz, bz));
            const float r  = sigmoid_f(acc[1][i] + fmaf(x, Kr, br));
            const float hh = tanh_f(fmaf(x, Kh, bhx) + r * (acc[2][i] + bhh));
            hn[i] = z * hprev[i] + (1.f - z) * hh;
            hprev[i] = hn[i];
        }
        __syncthreads();   // all A-fragment reads of old h complete

        #pragma unroll
        for (int i = 0; i < 4; ++i) {
            const int idx = ((j >> 3) * 16 + (r0 + i)) * 8 + (j & 7);
            hA[idx] = (_Float16)hn[i];
        }

        const int s = step - 47;
        if (s >= 0) {
            // dense_var: x2[b][o] = sum_j h[b][j] * w_o(j) + bias_o
            const float2 e = *reinterpret_cast<const float2*>(&dv_eps[s * 258 + 2 * j]);
            const float w0 = fmaf(ws0, e.x, wl0);
            const float w1 = fmaf(ws1, e.y, wl1);
            float pv[8];
            #pragma unroll
            for (int i = 0; i < 4; ++i) {
                pv[2 * i]     = hn[i] * w0;
                pv[2 * i + 1] = hn[i] * w1;
            }
            #pragma unroll
            for (int off = 8; off >= 1; off >>= 1) {
                #pragma unroll
                for (int k = 0; k < 8; ++k)
                    pv[k] += __shfl_xor(pv[k], off, 64);
            }
            if (m16 == 0) {
                #pragma unroll
                for (int i = 0; i < 4; ++i)
                    *reinterpret_cast<float2*>(&wsum[wv][r0 + i][0]) =
                        make_float2(pv[2 * i], pv[2 * i + 1]);
            }
            __syncthreads();   // h writes + wsum visible
            if (tid < TB) {
                const int bl = tid;
                const float eb0 = dv_eps[s * 258 + 256];
                const float eb1 = dv_eps[s * 258 + 257];
                float x20 = fmaf(wbs0, eb0, wbl0);
                float x21 = fmaf(wbs1, eb1, wbl1);
                #pragma unroll
                for (int w = 0; w < 8; ++w) {
                    x20 += wsum[w][bl][0];
                    x21 += wsum[w][bl][1];
                }
                const float scale = 1e-5f + 0.05f * softplus_f(Cc + x21);
                const size_t ob = ((size_t)(b0 + bl) * GAMMA + s) * 2;
                out[ob]     = x20;
                out[ob + 1] = scale;
                if (s < GAMMA - 1)
                    y_lds[bl] = fmaf(scale, samp[(size_t)s * B + b0 + bl], x20);
            }
            __syncthreads();   // y_lds visible for next step
        } else {
            __syncthreads();   // h writes visible for next matmul
        }
    }
}

extern "C" void kernel_launch(void* const* d_in, const int* in_sizes, int n_in,
                              void* d_out, int out_size, void* d_ws, size_t ws_size,
                              hipStream_t stream) {
    const float* inp    = (const float*)d_in[0];
    const float* Kw     = (const float*)d_in[1];
    const float* Rw     = (const float*)d_in[2];
    const float* bias   = (const float*)d_in[3];
    const float* dv_loc = (const float*)d_in[4];
    const float* dv_rho = (const float*)d_in[5];
    const float* dv_eps = (const float*)d_in[6];
    const float* samp   = (const float*)d_in[7];
    float* out = (float*)d_out;
    const int B = in_sizes[0] / 49;   // 8192
    dim3 grid(B / TB), block(NT);
    hipLaunchKernelGGL(fib_rnn_kernel, grid, block, 0, stream,
                       inp, Kw, Rw, bias, dv_loc, dv_rho, dv_eps, samp, out, B);
}